// Round 9
// baseline (143.872 us; speedup 1.0000x reference)
//
#include <hip/hip_runtime.h>
#include <hip/hip_bf16.h>

typedef _Float16 f16;
typedef _Float16 h4 __attribute__((ext_vector_type(4)));

#define B_   128
#define PP_  1024
#define LP_  128
#define H_   256

// tbl rows (f16, 178 x 256): PE 0..127 = Ee@Wd1; PA 128..159 = Ea@Wd1;
// PB 160..161 = Eb@Wd1 + bd1; PL 162..177 = El@Wd1 + bd1.
// stbl rows (f16, 8208 x 256): combo<8192: silu(PE[el]+PA[aa]+PB[bb]),
//   combo = el*64 + aa*2 + bb; rows 8192..8207: silu(PL[t]).
// ysum: [0,32768) P pools, [32768,65536) L pools.

// ---------------------------------------------------------------- kernel A
// bid 0..177: project one embedding row through Wd1 -> f16 tbl row.
// bid 178..305: contact features for batch b = bid-178 -> cbuf.
// bids 0..255 also zero ysum.
__global__ void __launch_bounds__(256) prep_k(
    const float* __restrict__ W1,
    const float* __restrict__ Ee, const float* __restrict__ Ea,
    const float* __restrict__ Eb, const float* __restrict__ El,
    const float* __restrict__ bd1,
    const float* __restrict__ ppos, const float* __restrict__ lpos,
    f16* __restrict__ tbl, float* __restrict__ cbuf, float* __restrict__ ysum)
{
  __shared__ float px[4 * 264], py[4 * 264], pz[4 * 264];
  __shared__ float lmin[128];
  __shared__ float src[256];
  const int bid = blockIdx.x, tid = threadIdx.x;
  if (bid < 256) ysum[bid * 256 + tid] = 0.f;

  if (bid < 178) {
    const float* s;
    float badd = 0.f;
    if (bid < 128)      s = Ee + bid * 256;
    else if (bid < 160) s = Ea + (bid - 128) * 256;
    else if (bid < 162) { s = Eb + (bid - 160) * 256; badd = bd1[tid]; }
    else                { s = El + (bid - 162) * 256; badd = bd1[tid]; }
    src[tid] = s[tid];
    __syncthreads();
    float a0 = 0.f, a1 = 0.f, a2 = 0.f, a3 = 0.f;
#pragma unroll 4
    for (int k = 0; k < 256; k += 4) {
      a0 += src[k]     * W1[(k)     * 256 + tid];
      a1 += src[k + 1] * W1[(k + 1) * 256 + tid];
      a2 += src[k + 2] * W1[(k + 2) * 256 + tid];
      a3 += src[k + 3] * W1[(k + 3) * 256 + tid];
    }
    tbl[bid * 256 + tid] = (f16)(((a0 + a1) + (a2 + a3)) + badd);
    return;
  }

  // ---- contact for batch b
  const int b = bid - 178;
#pragma unroll
  for (int r = 0; r < 4; ++r) {
    const int i = r * 256 + tid;
    const int d = (i >> 8) * 264 + (i & 255);
    const float* p = ppos + ((size_t)b * PP_ + i) * 3;
    px[d] = p[0]; py[d] = p[1]; pz[d] = p[2];
  }
  __syncthreads();
  {
    const int lig = tid >> 1, prt = tid & 1;
    const float* lp = lpos + ((size_t)b * LP_ + lig) * 3;
    const float lx = lp[0], ly = lp[1], lz = lp[2];
    float m = 3.4e38f;
#pragma unroll 1
    for (int s2 = prt * 2; s2 < prt * 2 + 2; ++s2) {
      const float4* X4 = (const float4*)(px + s2 * 264);
      const float4* Y4 = (const float4*)(py + s2 * 264);
      const float4* Z4 = (const float4*)(pz + s2 * 264);
#pragma unroll 4
      for (int i = 0; i < 64; ++i) {
        float4 X = X4[i], Y = Y4[i], Z = Z4[i];
        float dx, dy, dz, d2;
        dx = lx - X.x; dy = ly - Y.x; dz = lz - Z.x;
        d2 = dx * dx + dy * dy + dz * dz; m = fminf(m, d2);
        dx = lx - X.y; dy = ly - Y.y; dz = lz - Z.y;
        d2 = dx * dx + dy * dy + dz * dz; m = fminf(m, d2);
        dx = lx - X.z; dy = ly - Y.z; dz = lz - Z.z;
        d2 = dx * dx + dy * dy + dz * dz; m = fminf(m, d2);
        dx = lx - X.w; dy = ly - Y.w; dz = lz - Z.w;
        d2 = dx * dx + dy * dy + dz * dz; m = fminf(m, d2);
      }
    }
    m = fminf(m, __shfl_xor(m, 1));
    if (prt == 0) lmin[lig] = sqrtf(m);
  }
  __syncthreads();
  if (tid < 64) {
    const float a0 = lmin[tid], a1 = lmin[tid + 64];
    float sm = a0 + a1, mn = fminf(a0, a1);
#pragma unroll
    for (int off = 32; off; off >>= 1) {
      sm += __shfl_down(sm, off);
      mn = fminf(mn, __shfl_down(mn, off));
    }
    if (tid == 0) {
      cbuf[b * 2 + 0] = sm * (1.f / (float)LP_);
      cbuf[b * 2 + 1] = mn;
    }
  }
}

// ---------------------------------------------------------------- kernel A2
// One block per combo row: stbl[combo] = silu(PE[el]+PA[aa]+PB[bb]) (f16),
// rows 8192+ are silu(PL[t]). 8192+16 = 8208 blocks.
__global__ void __launch_bounds__(256) combo_k(
    const f16* __restrict__ tbl, f16* __restrict__ stbl)
{
  const int bid = blockIdx.x, tid = threadIdx.x;
  float pre;
  if (bid < 8192) {
    const int el = bid >> 6, aa = (bid >> 1) & 31, bb = bid & 1;
    pre = (float)tbl[el * 256 + tid]
        + (float)tbl[32768 + aa * 256 + tid]
        + (float)tbl[40960 + bb * 256 + tid];
  } else {
    pre = (float)tbl[41472 + (bid - 8192) * 256 + tid];
  }
  stbl[bid * 256 + tid] = (f16)(pre * __builtin_amdgcn_rcpf(1.f + __expf(-pre)));
}

// ---------------------------------------------------------------- kernel B
// Block = (batch, g): g<8 -> 128 protein rows, g==8 -> 128 ligand rows.
// Wave owns 32 rows; lane owns 4 cols (h4). One gather per row from stbl.
__global__ void __launch_bounds__(256, 4) gpool_k(
    const int* __restrict__ pel, const int* __restrict__ paa,
    const int* __restrict__ pbb, const int* __restrict__ ltyp,
    const f16* __restrict__ stbl, float* __restrict__ ysum)
{
  const int tid = threadIdx.x;
  const int wave = __builtin_amdgcn_readfirstlane(tid >> 6);
  const int lane = tid & 63;
  const int batch = blockIdx.x / 9, g = blockIdx.x % 9;
  const int c0 = lane * 4;
  float acc[4] = {0.f, 0.f, 0.f, 0.f};

  if (g < 8) {
    const int base = batch * PP_ + g * 128 + wave * 32;
#pragma unroll
    for (int ch = 0; ch < 4; ++ch) {
      const int cb = base + ch * 8;
      const int4 e0 = *(const int4*)(pel + cb), e1 = *(const int4*)(pel + cb + 4);
      const int4 a0 = *(const int4*)(paa + cb), a1 = *(const int4*)(paa + cb + 4);
      const int4 b0 = *(const int4*)(pbb + cb), b1 = *(const int4*)(pbb + cb + 4);
      const int cmb[8] = {
        e0.x * 64 + a0.x * 2 + b0.x, e0.y * 64 + a0.y * 2 + b0.y,
        e0.z * 64 + a0.z * 2 + b0.z, e0.w * 64 + a0.w * 2 + b0.w,
        e1.x * 64 + a1.x * 2 + b1.x, e1.y * 64 + a1.y * 2 + b1.y,
        e1.z * 64 + a1.z * 2 + b1.z, e1.w * 64 + a1.w * 2 + b1.w };
      h4 s[8];
#pragma unroll
      for (int r = 0; r < 8; ++r)
        s[r] = *(const h4*)(stbl + cmb[r] * 256 + c0);
#pragma unroll
      for (int r = 0; r < 8; ++r)
#pragma unroll
        for (int i = 0; i < 4; ++i)
          acc[i] += (float)s[r][i];
    }
    float* pool = ysum + batch * 256 + c0;
#pragma unroll
    for (int i = 0; i < 4; ++i) atomicAdd(pool + i, acc[i]);
  } else {
    const int base = batch * LP_ + wave * 32;
#pragma unroll
    for (int ch = 0; ch < 4; ++ch) {
      const int cb = base + ch * 8;
      const int4 l0 = *(const int4*)(ltyp + cb), l1 = *(const int4*)(ltyp + cb + 4);
      const int lt[8] = {l0.x, l0.y, l0.z, l0.w, l1.x, l1.y, l1.z, l1.w};
      h4 s[8];
#pragma unroll
      for (int r = 0; r < 8; ++r)
        s[r] = *(const h4*)(stbl + (8192 + lt[r]) * 256 + c0);
#pragma unroll
      for (int r = 0; r < 8; ++r)
#pragma unroll
        for (int i = 0; i < 4; ++i)
          acc[i] += (float)s[r][i];
    }
    float* pool = ysum + 32768 + batch * 256 + c0;
#pragma unroll
    for (int i = 0; i < 4; ++i) atomicAdd(pool + i, acc[i]);
  }
}

// ---------------------------------------------------------------- kernel C
// One 1024-thread block per batch: pooled = ys@Wd2/cnt + bd2 (K split 2-way),
// pre = pooled@Wa1 (K split 4-way) + ba1 + contact terms; out = silu(pre)@Wa2+ba2.
__global__ void __launch_bounds__(1024) head_k(
    const float* __restrict__ ysum, const float* __restrict__ cbuf,
    const float* __restrict__ W2, const float* __restrict__ bd2,
    const float* __restrict__ Wa1, const float* __restrict__ ba1,
    const float* __restrict__ Wa2, const float* __restrict__ ba2,
    float* __restrict__ out)
{
  __shared__ float ys[512], pooled[512], p2[1024], part[1024], red[4];
  const int b = blockIdx.x, tid = threadIdx.x;

  if (tid < 512)
    ys[tid] = (tid < 256) ? ysum[b * 256 + tid]
                          : ysum[32768 + b * 256 + (tid - 256)];
  __syncthreads();

  {
    const int kh2 = tid >> 9, h = (tid >> 8) & 1, n = tid & 255;
    const float* y = ys + h * 256 + kh2 * 128;
    const float* W = W2 + kh2 * 128 * 256 + n;
    float a[8];
#pragma unroll
    for (int u = 0; u < 8; ++u) a[u] = 0.f;
#pragma unroll 2
    for (int k = 0; k < 128; k += 8)
#pragma unroll
      for (int u = 0; u < 8; ++u)
        a[u] += y[k + u] * W[(k + u) * 256];
    p2[tid] = ((a[0] + a[1]) + (a[2] + a[3])) + ((a[4] + a[5]) + (a[6] + a[7]));
  }
  __syncthreads();
  if (tid < 512) {
    const int h = tid >> 8, n = tid & 255;
    const float scale = h ? (1.f / (float)LP_) : (1.f / (float)PP_);
    pooled[tid] = (p2[tid] + p2[512 + tid]) * scale + bd2[n];
  }
  __syncthreads();

  {
    const int kq = tid >> 8, j = tid & 255;
    const float* p = pooled + kq * 128;
    const float* W = Wa1 + kq * 128 * 256 + j;
    float a[8];
#pragma unroll
    for (int u = 0; u < 8; ++u) a[u] = 0.f;
#pragma unroll 2
    for (int n = 0; n < 128; n += 8)
#pragma unroll
      for (int u = 0; u < 8; ++u)
        a[u] += p[n + u] * W[(n + u) * 256];
    part[tid] = ((a[0] + a[1]) + (a[2] + a[3])) + ((a[4] + a[5]) + (a[6] + a[7]));
  }
  __syncthreads();

  if (tid < 256) {
    const float c0 = cbuf[b * 2], c1 = cbuf[b * 2 + 1];
    float pre = (part[tid] + part[256 + tid]) + (part[512 + tid] + part[768 + tid])
              + ba1[tid] + c0 * Wa1[512 * 256 + tid] + c1 * Wa1[513 * 256 + tid];
    float si = pre * __builtin_amdgcn_rcpf(1.f + __expf(-pre));
    float p = si * Wa2[tid];
#pragma unroll
    for (int off = 32; off; off >>= 1) p += __shfl_down(p, off);
    if ((tid & 63) == 0) red[tid >> 6] = p;
  }
  __syncthreads();
  if (tid == 0) out[b] = (red[0] + red[1]) + (red[2] + red[3]) + ba2[0];
}

// ---------------------------------------------------------------- launch
extern "C" void kernel_launch(void* const* d_in, const int* in_sizes, int n_in,
                              void* d_out, int out_size, void* d_ws, size_t ws_size,
                              hipStream_t stream)
{
  const float* protein_pos = (const float*)d_in[0];
  const float* ligand_pos  = (const float*)d_in[1];
  const int*   pel  = (const int*)d_in[2];
  const int*   paa  = (const int*)d_in[3];
  const int*   pbb  = (const int*)d_in[4];
  const int*   ltyp = (const int*)d_in[5];
  const float* Ee  = (const float*)d_in[8];
  const float* Ea  = (const float*)d_in[9];
  const float* Eb  = (const float*)d_in[10];
  const float* El  = (const float*)d_in[11];
  const float* Wd1 = (const float*)d_in[12];
  const float* bd1 = (const float*)d_in[13];
  const float* Wd2 = (const float*)d_in[14];
  const float* bd2 = (const float*)d_in[15];
  const float* Wa1 = (const float*)d_in[16];
  const float* ba1 = (const float*)d_in[17];
  const float* Wa2 = (const float*)d_in[18];
  const float* ba2 = (const float*)d_in[19];
  float* out = (float*)d_out;

  char* ws = (char*)d_ws;
  f16*   tbl  = (f16*)(ws);              // 178*256 f16 = 91136 B
  float* cbuf = (float*)(ws + 98304);    // 1024 B
  float* ysum = (float*)(ws + 102400);   // 65536 f32 = 262144 B
  f16*   stbl = (f16*)(ws + 524288);     // 8208*256 f16 = 4202496 B

  prep_k<<<306, 256, 0, stream>>>(Wd1, Ee, Ea, Eb, El, bd1,
                                  protein_pos, ligand_pos, tbl, cbuf, ysum);
  combo_k<<<8208, 256, 0, stream>>>(tbl, stbl);
  gpool_k<<<B_ * 9, 256, 0, stream>>>(pel, paa, pbb, ltyp, stbl, ysum);
  head_k<<<B_, 1024, 0, stream>>>(ysum, cbuf, Wd2, bd2, Wa1, ba1, Wa2, ba2, out);
}